// Round 7
// baseline (223.114 us; speedup 1.0000x reference)
//
#include <hip/hip_runtime.h>
#include <math.h>

#define ALPHA 0.2f

constexpr int F_IN  = 512;
constexpr int HO    = 256;   // H*O
constexpr int NHEAD = 8;

using bf16x8 = __attribute__((ext_vector_type(8))) short;
using bf16x4 = __attribute__((ext_vector_type(4))) short;
using f32x4  = __attribute__((ext_vector_type(4))) float;

__device__ __forceinline__ ushort f2bf(float f) {
    uint u = __float_as_uint(f);
    uint r = (u + 0x7FFFu + ((u >> 16) & 1u)) >> 16;   // RNE
    return (ushort)r;
}
__device__ __forceinline__ float bf2f(ushort b) {
    return __uint_as_float(((uint)b) << 16);
}

// ---------------- prep: W fragment pack (blocks 0..63) + dst rank/histogram ----------------
__global__ __launch_bounds__(256) void prep_kernel(const float* __restrict__ W,
                                                   ushort* __restrict__ Wf,
                                                   const int* __restrict__ dst,
                                                   int* __restrict__ cnt,
                                                   int* __restrict__ rnk, int E) {
    const int bid = blockIdx.x;
    const int t = threadIdx.x;
    if (bid < 64) {
        int g = bid * 256 + t;                   // 0..16383
        int l   = g & 63;
        int oct = (g >> 6) & 15;
        int ks  = g >> 10;
        int oc  = oct * 16 + (l & 15);
        int hh  = oc >> 5, oo = oc & 31;
        int kb  = ks * 32 + (l >> 4) * 8;
        ushort v[8];
#pragma unroll
        for (int j = 0; j < 8; ++j)
            v[j] = f2bf(W[((size_t)hh * F_IN + kb + j) * 32 + oo]);
        bf16x8 o = { (short)v[0], (short)v[1], (short)v[2], (short)v[3],
                     (short)v[4], (short)v[5], (short)v[6], (short)v[7] };
        *(bf16x8*)(Wf + (size_t)g * 8) = o;
    } else {
        int base = (bid - 64) * 1024;
#pragma unroll
        for (int q = 0; q < 4; ++q) {
            int i = base + q * 256 + t;
            if (i < E) rnk[i] = atomicAdd(&cnt[dst[i]], 1);
        }
    }
}

// ---------------- scan (3-phase) ----------------
__global__ __launch_bounds__(256) void scan1_kernel(const int* __restrict__ cnt,
                                                    int* __restrict__ bsum, int N) {
    __shared__ int red[256];
    const int t = threadIdx.x;
    const int b0 = blockIdx.x * 1024;
    int s = 0;
#pragma unroll
    for (int q = 0; q < 4; ++q) {
        int i = b0 + t * 4 + q;
        if (i < N) s += cnt[i];
    }
    red[t] = s;
    __syncthreads();
    for (int st = 128; st > 0; st >>= 1) {
        if (t < st) red[t] += red[t + st];
        __syncthreads();
    }
    if (t == 0) bsum[blockIdx.x] = red[0];
}

__global__ __launch_bounds__(64) void scan2_kernel(int* __restrict__ bsum, int nblk) {
    int l = threadIdx.x;
    int x = (l < nblk) ? bsum[l] : 0;
    int inc = x;
    for (int d = 1; d < 64; d <<= 1) {
        int v = __shfl_up(inc, d);
        if (l >= d) inc += v;
    }
    if (l < nblk) bsum[l] = inc - x;   // exclusive
}

__global__ __launch_bounds__(256) void scan3_kernel(const int* __restrict__ cnt,
                                                    const int* __restrict__ bsum,
                                                    int* __restrict__ off, int N, int E) {
    __shared__ int part[256];
    const int t = threadIdx.x;
    const int b0 = blockIdx.x * 1024;
    int v[4];
    int s = 0;
#pragma unroll
    for (int q = 0; q < 4; ++q) {
        int i = b0 + t * 4 + q;
        v[q] = (i < N) ? cnt[i] : 0;
        s += v[q];
    }
    part[t] = s;
    __syncthreads();
    for (int d = 1; d < 256; d <<= 1) {
        int x = (t >= d) ? part[t - d] : 0;
        __syncthreads();
        part[t] += x;
        __syncthreads();
    }
    int run = bsum[blockIdx.x] + ((t == 0) ? 0 : part[t - 1]);
#pragma unroll
    for (int q = 0; q < 4; ++q) {
        int i = b0 + t * 4 + q;
        if (i < N) { off[i] = run; run += v[q]; }
    }
    if (blockIdx.x == 0 && t == 0) off[N] = E;
}

// ---------------- place: se[off[dst]+rnk] = src  (no atomics) ----------------
__global__ __launch_bounds__(256) void place_kernel(const int* __restrict__ src,
                                                    const int* __restrict__ dst,
                                                    const int* __restrict__ rnk,
                                                    const int* __restrict__ off,
                                                    int* __restrict__ se, int E) {
    int base = blockIdx.x * 1024;
#pragma unroll
    for (int q = 0; q < 4; ++q) {
        int i = base + q * 256 + threadIdx.x;
        if (i < E) se[off[dst[i]] + rnk[i]] = src[i];
    }
}

// ---------------- MFMA GEMM: tile 128 nodes x 256 outs; 4 waves ----------------
// outputs HEAD-MAJOR: Wh[h][node][32], es[h][node], ed[h][node]
__global__ __launch_bounds__(256, 2) void gemm_kernel(
    const float* __restrict__ h, const ushort* __restrict__ Wf,
    const float* __restrict__ Wb, const float* __restrict__ a,
    ushort* __restrict__ Wh, float* __restrict__ es, float* __restrict__ ed, int N)
{
    __shared__ ushort hs[2][128 * 40];    // 128 rows x 32 k bf16, pitch 40 (80 B)
    const int t = threadIdx.x;
    const int l = t & 63;
    const int w = t >> 6;
    const int l15 = l & 15, l4 = l >> 4;
    const int n0 = blockIdx.x * 128;

    const int sr = t >> 1;                 // staging row 0..127
    const int sc = (t & 1) * 16;           // staging k col 0 or 16
    int srow = n0 + sr; if (srow >= N) srow = N - 1;
    const float* hrow = h + (size_t)srow * F_IN + sc;

    f32x4 acc[4][8];
#pragma unroll
    for (int i = 0; i < 4; ++i)
#pragma unroll
        for (int nt = 0; nt < 8; ++nt) acc[i][nt] = (f32x4){0.f, 0.f, 0.f, 0.f};

    // prologue: stage ks=0 (16 floats -> 16 bf16)
    {
        float4 v0 = *(const float4*)(hrow);
        float4 v1 = *(const float4*)(hrow + 4);
        float4 v2 = *(const float4*)(hrow + 8);
        float4 v3 = *(const float4*)(hrow + 12);
        bf16x8 o0 = { (short)f2bf(v0.x), (short)f2bf(v0.y), (short)f2bf(v0.z), (short)f2bf(v0.w),
                      (short)f2bf(v1.x), (short)f2bf(v1.y), (short)f2bf(v1.z), (short)f2bf(v1.w) };
        bf16x8 o1 = { (short)f2bf(v2.x), (short)f2bf(v2.y), (short)f2bf(v2.z), (short)f2bf(v2.w),
                      (short)f2bf(v3.x), (short)f2bf(v3.y), (short)f2bf(v3.z), (short)f2bf(v3.w) };
        *(bf16x8*)&hs[0][sr * 40 + sc]     = o0;
        *(bf16x8*)&hs[0][sr * 40 + sc + 8] = o1;
    }
    __syncthreads();

    for (int ks = 0; ks < 16; ++ks) {
        const int cb = ks & 1;
        float4 nx0, nx1, nx2, nx3;
        if (ks < 15) {
            const float* p = hrow + (ks + 1) * 32;
            nx0 = *(const float4*)(p);
            nx1 = *(const float4*)(p + 4);
            nx2 = *(const float4*)(p + 8);
            nx3 = *(const float4*)(p + 12);
        }
        bf16x8 af[4];
#pragma unroll
        for (int i = 0; i < 4; ++i)
            af[i] = *(const bf16x8*)(Wf + ((size_t)((ks * 16 + 4 * w + i) * 64 + l)) * 8);
#pragma unroll
        for (int half = 0; half < 2; ++half) {
            bf16x8 b4[4];
#pragma unroll
            for (int j = 0; j < 4; ++j)
                b4[j] = *(const bf16x8*)&hs[cb][((half * 4 + j) * 16 + l15) * 40 + l4 * 8];
#pragma unroll
            for (int i = 0; i < 4; ++i)
#pragma unroll
                for (int j = 0; j < 4; ++j)
                    acc[i][half * 4 + j] = __builtin_amdgcn_mfma_f32_16x16x32_bf16(
                        af[i], b4[j], acc[i][half * 4 + j], 0, 0, 0);
        }
        if (ks < 15) {
            bf16x8 o0 = { (short)f2bf(nx0.x), (short)f2bf(nx0.y), (short)f2bf(nx0.z), (short)f2bf(nx0.w),
                          (short)f2bf(nx1.x), (short)f2bf(nx1.y), (short)f2bf(nx1.z), (short)f2bf(nx1.w) };
            bf16x8 o1 = { (short)f2bf(nx2.x), (short)f2bf(nx2.y), (short)f2bf(nx2.z), (short)f2bf(nx2.w),
                          (short)f2bf(nx3.x), (short)f2bf(nx3.y), (short)f2bf(nx3.z), (short)f2bf(nx3.w) };
            *(bf16x8*)&hs[cb ^ 1][sr * 40 + sc]     = o0;
            *(bf16x8*)&hs[cb ^ 1][sr * 40 + sc + 8] = o1;
            __syncthreads();
        }
    }

    // epilogue (head-major outputs)
    float4 wb4[4], as4[4], ad4[4];
    int ocb[4];
#pragma unroll
    for (int i = 0; i < 4; ++i) {
        int oc_base = (4 * w + i) * 16 + (l4 << 2);
        ocb[i] = oc_base;
        int head = oc_base >> 5;
        wb4[i] = *(const float4*)(Wb + oc_base);
        as4[i] = *(const float4*)(a + head * 64 + (oc_base & 31));
        ad4[i] = *(const float4*)(a + head * 64 + 32 + (oc_base & 31));
    }
#pragma unroll
    for (int nt = 0; nt < 8; ++nt) {
        int node = n0 + nt * 16 + l15;
        bool ok = node < N;
        float pe[4] = {0.f, 0.f, 0.f, 0.f};   // es_h0, es_h1, ed_h0, ed_h1
#pragma unroll
        for (int i = 0; i < 4; ++i) {
            f32x4 v = acc[i][nt];
            float r0 = v.x + wb4[i].x, r1 = v.y + wb4[i].y;
            float r2 = v.z + wb4[i].z, r3 = v.w + wb4[i].w;
            if (ok) {
                int head = ocb[i] >> 5, oo = ocb[i] & 31;
                bf16x4 o = { (short)f2bf(r0), (short)f2bf(r1), (short)f2bf(r2), (short)f2bf(r3) };
                *(bf16x4*)(Wh + ((size_t)head * N + node) * 32 + oo) = o;
            }
            float dsv = r0 * as4[i].x + r1 * as4[i].y + r2 * as4[i].z + r3 * as4[i].w;
            float ddv = r0 * ad4[i].x + r1 * ad4[i].y + r2 * ad4[i].z + r3 * ad4[i].w;
            int hp = i >> 1;
            pe[hp] += dsv; pe[2 + hp] += ddv;
        }
#pragma unroll
        for (int q = 0; q < 4; ++q) {
            pe[q] += __shfl_xor(pe[q], 16);
            pe[q] += __shfl_xor(pe[q], 32);
        }
        if (l4 == 0 && ok) {
            es[(size_t)(2 * w)     * N + node] = pe[0];
            es[(size_t)(2 * w + 1) * N + node] = pe[1];
            ed[(size_t)(2 * w)     * N + node] = pe[2];
            ed[(size_t)(2 * w + 1) * N + node] = pe[3];
        }
    }
}

// ---------------- aggregate: head-split across XCDs, single pass, no LDS ----------------
// blockIdx % 8 = head (lands on one XCD under round-robin dispatch -> 3.2 MB
// Wh head-slice is L2-resident). 4 waves x 2 nodes each = 8 nodes/block.
// Wave: 8 edge-slots x 8 lanes; slot gathers one 64 B Wh row per edge.
__global__ __launch_bounds__(256) void node_kernel(
    const int* __restrict__ se, const int* __restrict__ off,
    const float* __restrict__ es, const float* __restrict__ ed,
    const float* __restrict__ ab, const ushort* __restrict__ Wh,
    float* __restrict__ out, int N)
{
    const int bid  = blockIdx.x;
    const int hg   = bid & 7;
    const int tile = bid >> 3;
    const int t    = threadIdx.x;
    const int l    = t & 63;
    const int wv   = t >> 6;
    const int slot = l >> 3;
    const int sub  = l & 7;

    const float abh = ab[hg];
    const ushort* WhH = Wh + (size_t)hg * N * 32;
    const float*  esH = es + (size_t)hg * N;
    const float*  edH = ed + (size_t)hg * N;

#pragma unroll
    for (int nn = 0; nn < 2; ++nn) {
        const int n = tile * 8 + wv * 2 + nn;
        if (n >= N) break;
        const int beg = off[n];
        const int deg = off[n + 1] - beg;
        const float base = edH[n] + abh;

        float a0 = 0.f, a1 = 0.f, a2 = 0.f, a3 = 0.f, dsum = 0.f;
        for (int j = slot; j < deg; j += 8) {
            int s = se[beg + j];
            float ev = esH[s] + base;
            ev = ev > 0.f ? ev : ALPHA * ev;
            float wj = __expf(ev);
            bf16x4 row = *(const bf16x4*)(WhH + (size_t)s * 32 + sub * 4);
            a0 += wj * bf2f((ushort)row[0]);
            a1 += wj * bf2f((ushort)row[1]);
            a2 += wj * bf2f((ushort)row[2]);
            a3 += wj * bf2f((ushort)row[3]);
            dsum += wj;
        }
        // reduce across the 8 slots (lane bits 3,4,5)
#pragma unroll
        for (int m = 8; m <= 32; m <<= 1) {
            a0 += __shfl_xor(a0, m);
            a1 += __shfl_xor(a1, m);
            a2 += __shfl_xor(a2, m);
            a3 += __shfl_xor(a3, m);
            dsum += __shfl_xor(dsum, m);
        }
        if (slot == 0) {
            float inv = dsum > 0.f ? 1.f / dsum : 1.f;
            float4 o = make_float4(a0 * inv, a1 * inv, a2 * inv, a3 * inv);
            *(float4*)(out + (size_t)n * HO + hg * 32 + sub * 4) = o;
        }
    }
}

// ---------------- launch ----------------
extern "C" void kernel_launch(void* const* d_in, const int* in_sizes, int n_in,
                              void* d_out, int out_size, void* d_ws, size_t ws_size,
                              hipStream_t stream) {
    const float* h   = (const float*)d_in[0];
    const int*   src = (const int*)  d_in[1];
    const int*   dst = (const int*)  d_in[2];
    const float* W   = (const float*)d_in[3];
    const float* Wb  = (const float*)d_in[4];
    const float* a   = (const float*)d_in[5];
    const float* ab  = (const float*)d_in[6];
    float* out = (float*)d_out;

    const int N = in_sizes[0] / F_IN;
    const int E = in_sizes[1];

    auto align_up = [](size_t x) { return (x + 255) & ~size_t(255); };
    char* p = (char*)d_ws;
    ushort* Wh = (ushort*)p; p += align_up((size_t)N * HO * 2);
    float*  es = (float*)p;  p += align_up((size_t)N * NHEAD * 4);
    float*  ed = (float*)p;  p += align_up((size_t)N * NHEAD * 4);
    int* cnt   = (int*)p;    p += align_up((size_t)N * 4);
    int* off   = (int*)p;    p += align_up((size_t)(N + 1) * 4);
    int* rnk   = (int*)p;    p += align_up((size_t)E * 4);
    int* se    = (int*)p;    p += align_up((size_t)E * 4);
    int* bsum  = (int*)p;    p += align_up((size_t)64 * 4);
    ushort* Wf = (ushort*)p; p += align_up((size_t)16 * 16 * 64 * 8 * 2);

    const int nblk = (N + 1023) / 1024;      // 49 for N=50000 (<= 64)
    const int EB   = (E + 1023) / 1024;      // 782 edge blocks
    const int GB   = (N + 127) / 128;        // 391 gemm blocks
    const int NT   = (N + 7) / 8;            // node tiles (8 nodes per block)

    hipMemsetAsync(cnt, 0, (size_t)N * sizeof(int), stream);
    prep_kernel<<<64 + EB, 256, 0, stream>>>(W, Wf, dst, cnt, rnk, E);
    scan1_kernel<<<nblk, 256, 0, stream>>>(cnt, bsum, N);
    scan2_kernel<<<1, 64, 0, stream>>>(bsum, nblk);
    scan3_kernel<<<nblk, 256, 0, stream>>>(cnt, bsum, off, N, E);
    place_kernel<<<EB, 256, 0, stream>>>(src, dst, rnk, off, se, E);
    gemm_kernel<<<GB, 256, 0, stream>>>(h, Wf, Wb, a, Wh, es, ed, N);
    node_kernel<<<NT * 8, 256, 0, stream>>>(se, off, es, ed, ab, Wh, out, N);
}

// Round 8
// 175.014 us; speedup vs baseline: 1.2748x; 1.2748x over previous
//
#include <hip/hip_runtime.h>
#include <math.h>

#define ALPHA 0.2f

constexpr int F_IN  = 512;
constexpr int HO    = 256;   // H*O
constexpr int NHEAD = 8;

using bf16x8 = __attribute__((ext_vector_type(8))) short;
using bf16x4 = __attribute__((ext_vector_type(4))) short;
using f32x4  = __attribute__((ext_vector_type(4))) float;

__device__ __forceinline__ ushort f2bf(float f) {
    uint u = __float_as_uint(f);
    uint r = (u + 0x7FFFu + ((u >> 16) & 1u)) >> 16;   // RNE
    return (ushort)r;
}
__device__ __forceinline__ float bf2f(ushort b) {
    return __uint_as_float(((uint)b) << 16);
}

// ---------------- prep: W fragment pack (blocks 0..63) + dst rank/histogram ----------------
__global__ __launch_bounds__(256) void prep_kernel(const float* __restrict__ W,
                                                   ushort* __restrict__ Wf,
                                                   const int* __restrict__ dst,
                                                   int* __restrict__ cnt,
                                                   int* __restrict__ rnk, int E) {
    const int bid = blockIdx.x;
    const int t = threadIdx.x;
    if (bid < 64) {
        int g = bid * 256 + t;                   // 0..16383
        int l   = g & 63;
        int oct = (g >> 6) & 15;
        int ks  = g >> 10;
        int oc  = oct * 16 + (l & 15);
        int hh  = oc >> 5, oo = oc & 31;
        int kb  = ks * 32 + (l >> 4) * 8;
        ushort v[8];
#pragma unroll
        for (int j = 0; j < 8; ++j)
            v[j] = f2bf(W[((size_t)hh * F_IN + kb + j) * 32 + oo]);
        bf16x8 o = { (short)v[0], (short)v[1], (short)v[2], (short)v[3],
                     (short)v[4], (short)v[5], (short)v[6], (short)v[7] };
        *(bf16x8*)(Wf + (size_t)g * 8) = o;
    } else {
        int base = (bid - 64) * 1024;
#pragma unroll
        for (int q = 0; q < 4; ++q) {
            int i = base + q * 256 + t;
            if (i < E) rnk[i] = atomicAdd(&cnt[dst[i]], 1);
        }
    }
}

// ---------------- scan (3-phase) ----------------
__global__ __launch_bounds__(256) void scan1_kernel(const int* __restrict__ cnt,
                                                    int* __restrict__ bsum, int N) {
    __shared__ int red[256];
    const int t = threadIdx.x;
    const int b0 = blockIdx.x * 1024;
    int s = 0;
#pragma unroll
    for (int q = 0; q < 4; ++q) {
        int i = b0 + t * 4 + q;
        if (i < N) s += cnt[i];
    }
    red[t] = s;
    __syncthreads();
    for (int st = 128; st > 0; st >>= 1) {
        if (t < st) red[t] += red[t + st];
        __syncthreads();
    }
    if (t == 0) bsum[blockIdx.x] = red[0];
}

__global__ __launch_bounds__(64) void scan2_kernel(int* __restrict__ bsum, int nblk) {
    int l = threadIdx.x;
    int x = (l < nblk) ? bsum[l] : 0;
    int inc = x;
    for (int d = 1; d < 64; d <<= 1) {
        int v = __shfl_up(inc, d);
        if (l >= d) inc += v;
    }
    if (l < nblk) bsum[l] = inc - x;   // exclusive
}

__global__ __launch_bounds__(256) void scan3_kernel(const int* __restrict__ cnt,
                                                    const int* __restrict__ bsum,
                                                    int* __restrict__ off, int N, int E) {
    __shared__ int part[256];
    const int t = threadIdx.x;
    const int b0 = blockIdx.x * 1024;
    int v[4];
    int s = 0;
#pragma unroll
    for (int q = 0; q < 4; ++q) {
        int i = b0 + t * 4 + q;
        v[q] = (i < N) ? cnt[i] : 0;
        s += v[q];
    }
    part[t] = s;
    __syncthreads();
    for (int d = 1; d < 256; d <<= 1) {
        int x = (t >= d) ? part[t - d] : 0;
        __syncthreads();
        part[t] += x;
        __syncthreads();
    }
    int run = bsum[blockIdx.x] + ((t == 0) ? 0 : part[t - 1]);
#pragma unroll
    for (int q = 0; q < 4; ++q) {
        int i = b0 + t * 4 + q;
        if (i < N) { off[i] = run; run += v[q]; }
    }
    if (blockIdx.x == 0 && t == 0) off[N] = E;
}

// ---------------- place: se[off[dst]+rnk] = src  (no atomics) ----------------
__global__ __launch_bounds__(256) void place_kernel(const int* __restrict__ src,
                                                    const int* __restrict__ dst,
                                                    const int* __restrict__ rnk,
                                                    const int* __restrict__ off,
                                                    int* __restrict__ se, int E) {
    int base = blockIdx.x * 1024;
#pragma unroll
    for (int q = 0; q < 4; ++q) {
        int i = base + q * 256 + threadIdx.x;
        if (i < E) se[off[dst[i]] + rnk[i]] = src[i];
    }
}

// ---------------- MFMA GEMM: tile 128 nodes x 256 outs; 4 waves ----------------
// outputs HEAD-MAJOR: Wh[h][node][32], es[h][node], ed[h][node]
__global__ __launch_bounds__(256, 2) void gemm_kernel(
    const float* __restrict__ h, const ushort* __restrict__ Wf,
    const float* __restrict__ Wb, const float* __restrict__ a,
    ushort* __restrict__ Wh, float* __restrict__ es, float* __restrict__ ed, int N)
{
    __shared__ ushort hs[2][128 * 40];    // 128 rows x 32 k bf16, pitch 40 (80 B)
    const int t = threadIdx.x;
    const int l = t & 63;
    const int w = t >> 6;
    const int l15 = l & 15, l4 = l >> 4;
    const int n0 = blockIdx.x * 128;

    const int sr = t >> 1;                 // staging row 0..127
    const int sc = (t & 1) * 16;           // staging k col 0 or 16
    int srow = n0 + sr; if (srow >= N) srow = N - 1;
    const float* hrow = h + (size_t)srow * F_IN + sc;

    f32x4 acc[4][8];
#pragma unroll
    for (int i = 0; i < 4; ++i)
#pragma unroll
        for (int nt = 0; nt < 8; ++nt) acc[i][nt] = (f32x4){0.f, 0.f, 0.f, 0.f};

    // prologue: stage ks=0 (16 floats -> 16 bf16)
    {
        float4 v0 = *(const float4*)(hrow);
        float4 v1 = *(const float4*)(hrow + 4);
        float4 v2 = *(const float4*)(hrow + 8);
        float4 v3 = *(const float4*)(hrow + 12);
        bf16x8 o0 = { (short)f2bf(v0.x), (short)f2bf(v0.y), (short)f2bf(v0.z), (short)f2bf(v0.w),
                      (short)f2bf(v1.x), (short)f2bf(v1.y), (short)f2bf(v1.z), (short)f2bf(v1.w) };
        bf16x8 o1 = { (short)f2bf(v2.x), (short)f2bf(v2.y), (short)f2bf(v2.z), (short)f2bf(v2.w),
                      (short)f2bf(v3.x), (short)f2bf(v3.y), (short)f2bf(v3.z), (short)f2bf(v3.w) };
        *(bf16x8*)&hs[0][sr * 40 + sc]     = o0;
        *(bf16x8*)&hs[0][sr * 40 + sc + 8] = o1;
    }
    __syncthreads();

    for (int ks = 0; ks < 16; ++ks) {
        const int cb = ks & 1;
        float4 nx0, nx1, nx2, nx3;
        if (ks < 15) {
            const float* p = hrow + (ks + 1) * 32;
            nx0 = *(const float4*)(p);
            nx1 = *(const float4*)(p + 4);
            nx2 = *(const float4*)(p + 8);
            nx3 = *(const float4*)(p + 12);
        }
        bf16x8 af[4];
#pragma unroll
        for (int i = 0; i < 4; ++i)
            af[i] = *(const bf16x8*)(Wf + ((size_t)((ks * 16 + 4 * w + i) * 64 + l)) * 8);
#pragma unroll
        for (int half = 0; half < 2; ++half) {
            bf16x8 b4[4];
#pragma unroll
            for (int j = 0; j < 4; ++j)
                b4[j] = *(const bf16x8*)&hs[cb][((half * 4 + j) * 16 + l15) * 40 + l4 * 8];
#pragma unroll
            for (int i = 0; i < 4; ++i)
#pragma unroll
                for (int j = 0; j < 4; ++j)
                    acc[i][half * 4 + j] = __builtin_amdgcn_mfma_f32_16x16x32_bf16(
                        af[i], b4[j], acc[i][half * 4 + j], 0, 0, 0);
        }
        if (ks < 15) {
            bf16x8 o0 = { (short)f2bf(nx0.x), (short)f2bf(nx0.y), (short)f2bf(nx0.z), (short)f2bf(nx0.w),
                          (short)f2bf(nx1.x), (short)f2bf(nx1.y), (short)f2bf(nx1.z), (short)f2bf(nx1.w) };
            bf16x8 o1 = { (short)f2bf(nx2.x), (short)f2bf(nx2.y), (short)f2bf(nx2.z), (short)f2bf(nx2.w),
                          (short)f2bf(nx3.x), (short)f2bf(nx3.y), (short)f2bf(nx3.z), (short)f2bf(nx3.w) };
            *(bf16x8*)&hs[cb ^ 1][sr * 40 + sc]     = o0;
            *(bf16x8*)&hs[cb ^ 1][sr * 40 + sc + 8] = o1;
            __syncthreads();
        }
    }

    // epilogue (head-major outputs)
    float4 wb4[4], as4[4], ad4[4];
    int ocb[4];
#pragma unroll
    for (int i = 0; i < 4; ++i) {
        int oc_base = (4 * w + i) * 16 + (l4 << 2);
        ocb[i] = oc_base;
        int head = oc_base >> 5;
        wb4[i] = *(const float4*)(Wb + oc_base);
        as4[i] = *(const float4*)(a + head * 64 + (oc_base & 31));
        ad4[i] = *(const float4*)(a + head * 64 + 32 + (oc_base & 31));
    }
#pragma unroll
    for (int nt = 0; nt < 8; ++nt) {
        int node = n0 + nt * 16 + l15;
        bool ok = node < N;
        float pe[4] = {0.f, 0.f, 0.f, 0.f};   // es_h0, es_h1, ed_h0, ed_h1
#pragma unroll
        for (int i = 0; i < 4; ++i) {
            f32x4 v = acc[i][nt];
            float r0 = v.x + wb4[i].x, r1 = v.y + wb4[i].y;
            float r2 = v.z + wb4[i].z, r3 = v.w + wb4[i].w;
            if (ok) {
                int head = ocb[i] >> 5, oo = ocb[i] & 31;
                bf16x4 o = { (short)f2bf(r0), (short)f2bf(r1), (short)f2bf(r2), (short)f2bf(r3) };
                *(bf16x4*)(Wh + ((size_t)head * N + node) * 32 + oo) = o;
            }
            float dsv = r0 * as4[i].x + r1 * as4[i].y + r2 * as4[i].z + r3 * as4[i].w;
            float ddv = r0 * ad4[i].x + r1 * ad4[i].y + r2 * ad4[i].z + r3 * ad4[i].w;
            int hp = i >> 1;
            pe[hp] += dsv; pe[2 + hp] += ddv;
        }
#pragma unroll
        for (int q = 0; q < 4; ++q) {
            pe[q] += __shfl_xor(pe[q], 16);
            pe[q] += __shfl_xor(pe[q], 32);
        }
        if (l4 == 0 && ok) {
            es[(size_t)(2 * w)     * N + node] = pe[0];
            es[(size_t)(2 * w + 1) * N + node] = pe[1];
            ed[(size_t)(2 * w)     * N + node] = pe[2];
            ed[(size_t)(2 * w + 1) * N + node] = pe[3];
        }
    }
}

// ---------------- aggregate: head-split across XCDs, 4-lane group per node ----------------
// blockIdx % 8 = head -> per-XCD working set = 3.2 MB Wh slice (L2-resident).
// Block: 256 thr = 64 nodes; group g = t>>2 owns node, lane sub = t&3 owns
// output slice sub*8..sub*8+7 (16 B bf16x8 per edge; group fetches the full
// contiguous 64 B row in one transaction). Serial edge loop, 2-deep unroll,
// NO cross-lane reduction (dsum computed redundantly in-group).
__global__ __launch_bounds__(256) void node_kernel(
    const int* __restrict__ se, const int* __restrict__ off,
    const float* __restrict__ es, const float* __restrict__ ed,
    const float* __restrict__ ab, const ushort* __restrict__ Wh,
    float* __restrict__ out, int N)
{
    const int bid  = blockIdx.x;
    const int hg   = bid & 7;
    const int tile = bid >> 3;
    const int t    = threadIdx.x;
    const int g    = t >> 2;
    const int sub  = t & 3;
    const int n    = tile * 64 + g;
    if (n >= N) return;

    const ushort* WhH = Wh + (size_t)hg * N * 32 + sub * 8;
    const float*  esH = es + (size_t)hg * N;

    const int beg = off[n];
    const int deg = off[n + 1] - beg;
    const float base = ed[(size_t)hg * N + n] + ab[hg];

    float acc[8] = {0.f, 0.f, 0.f, 0.f, 0.f, 0.f, 0.f, 0.f};
    float dsum = 0.f;

    int j = 0;
    for (; j + 1 < deg; j += 2) {
        int s0 = se[beg + j];
        int s1 = se[beg + j + 1];
        float ev0 = esH[s0] + base;
        float ev1 = esH[s1] + base;
        bf16x8 r0 = *(const bf16x8*)(WhH + (size_t)s0 * 32);
        bf16x8 r1 = *(const bf16x8*)(WhH + (size_t)s1 * 32);
        ev0 = ev0 > 0.f ? ev0 : ALPHA * ev0;
        ev1 = ev1 > 0.f ? ev1 : ALPHA * ev1;
        float w0 = __expf(ev0);
        float w1 = __expf(ev1);
#pragma unroll
        for (int i = 0; i < 8; ++i) acc[i] += w0 * bf2f((ushort)r0[i]);
#pragma unroll
        for (int i = 0; i < 8; ++i) acc[i] += w1 * bf2f((ushort)r1[i]);
        dsum += w0 + w1;
    }
    if (j < deg) {
        int s0 = se[beg + j];
        float ev0 = esH[s0] + base;
        bf16x8 r0 = *(const bf16x8*)(WhH + (size_t)s0 * 32);
        ev0 = ev0 > 0.f ? ev0 : ALPHA * ev0;
        float w0 = __expf(ev0);
#pragma unroll
        for (int i = 0; i < 8; ++i) acc[i] += w0 * bf2f((ushort)r0[i]);
        dsum += w0;
    }

    float inv = dsum > 0.f ? 1.f / dsum : 1.f;
    float* op = out + (size_t)n * HO + hg * 32 + sub * 8;
    *(float4*)(op)     = make_float4(acc[0] * inv, acc[1] * inv, acc[2] * inv, acc[3] * inv);
    *(float4*)(op + 4) = make_float4(acc[4] * inv, acc[5] * inv, acc[6] * inv, acc[7] * inv);
}

// ---------------- launch ----------------
extern "C" void kernel_launch(void* const* d_in, const int* in_sizes, int n_in,
                              void* d_out, int out_size, void* d_ws, size_t ws_size,
                              hipStream_t stream) {
    const float* h   = (const float*)d_in[0];
    const int*   src = (const int*)  d_in[1];
    const int*   dst = (const int*)  d_in[2];
    const float* W   = (const float*)d_in[3];
    const float* Wb  = (const float*)d_in[4];
    const float* a   = (const float*)d_in[5];
    const float* ab  = (const float*)d_in[6];
    float* out = (float*)d_out;

    const int N = in_sizes[0] / F_IN;
    const int E = in_sizes[1];

    auto align_up = [](size_t x) { return (x + 255) & ~size_t(255); };
    char* p = (char*)d_ws;
    ushort* Wh = (ushort*)p; p += align_up((size_t)N * HO * 2);
    float*  es = (float*)p;  p += align_up((size_t)N * NHEAD * 4);
    float*  ed = (float*)p;  p += align_up((size_t)N * NHEAD * 4);
    int* cnt   = (int*)p;    p += align_up((size_t)N * 4);
    int* off   = (int*)p;    p += align_up((size_t)(N + 1) * 4);
    int* rnk   = (int*)p;    p += align_up((size_t)E * 4);
    int* se    = (int*)p;    p += align_up((size_t)E * 4);
    int* bsum  = (int*)p;    p += align_up((size_t)64 * 4);
    ushort* Wf = (ushort*)p; p += align_up((size_t)16 * 16 * 64 * 8 * 2);

    const int nblk = (N + 1023) / 1024;      // 49 for N=50000 (<= 64)
    const int EB   = (E + 1023) / 1024;      // 782 edge blocks
    const int GB   = (N + 127) / 128;        // 391 gemm blocks
    const int NT   = (N + 63) / 64;          // node tiles (64 nodes per block)

    hipMemsetAsync(cnt, 0, (size_t)N * sizeof(int), stream);
    prep_kernel<<<64 + EB, 256, 0, stream>>>(W, Wf, dst, cnt, rnk, E);
    scan1_kernel<<<nblk, 256, 0, stream>>>(cnt, bsum, N);
    scan2_kernel<<<1, 64, 0, stream>>>(bsum, nblk);
    scan3_kernel<<<nblk, 256, 0, stream>>>(cnt, bsum, off, N, E);
    place_kernel<<<EB, 256, 0, stream>>>(src, dst, rnk, off, se, E);
    gemm_kernel<<<GB, 256, 0, stream>>>(h, Wf, Wb, a, Wh, es, ed, N);
    node_kernel<<<NT * 8, 256, 0, stream>>>(se, off, es, ed, ab, Wh, out, N);
}